// Round 7
// baseline (1520.073 us; speedup 1.0000x reference)
//
#include <hip/hip_runtime.h>

#define B_   16
#define SEQ  512
#define MM   514      // SEQ + 2 memory tokens
#define HID  1024
#define NH   16
#define DH   64
#define UNI  (1.0f/514.0f)

typedef unsigned short us;
typedef __attribute__((ext_vector_type(4))) float f32x4;

__device__ __forceinline__ us f2bf(float f) {  // RNE f32->bf16
  unsigned int u = __float_as_uint(f);
  u = (u + 0x7FFFu + ((u >> 16) & 1u)) >> 16;
  return (us)u;
}
__device__ __forceinline__ float bf2f(us h) {
  return __uint_as_float(((unsigned int)h) << 16);
}

// ---------------------------------------------------------------------------
// K1: proj. P[b,t,o] = sum_k Mem(t,k)*W[o,k].  f32 VALU, 128x128 tile,
// 8x8 register blocking, K staged 32 deep with transpose-on-write.
// fmt=1: store P as f32; fmt=0: store bf16.
// ---------------------------------------------------------------------------
__global__ __launch_bounds__(256) void proj_kernel(
    const float* __restrict__ tin, const float* __restrict__ mvec,
    const float* __restrict__ W, void* __restrict__ P, const int fmt) {
  const int otile = blockIdx.x, ttile = blockIdx.y, b = blockIdx.z;
  const int t0 = ttile * 128, o0 = otile * 128;
  __shared__ __align__(16) float Ss[32 * 132];  // [k][t]
  __shared__ __align__(16) float Ws[32 * 132];  // [k][o]
  const int tid = threadIdx.x;

  float acc[8][8];
#pragma unroll
  for (int i = 0; i < 8; i++)
#pragma unroll
    for (int j = 0; j < 8; j++) acc[i][j] = 0.f;

  const int tr = tid >> 1, half = tid & 1;   // staging: 128 rows x 2 halves
  const int tg = t0 + tr;
  const float* arow = (tg < 2) ? (mvec + (size_t)tg * HID)
                    : (tg < MM) ? (tin + ((size_t)(b * SEQ + tg - 2)) * HID)
                                : nullptr;
  const float* wrow = W + (size_t)(o0 + tr) * HID;

  for (int kk = 0; kk < HID; kk += 32) {
    __syncthreads();
#pragma unroll
    for (int c = 0; c < 4; c++) {
      f32x4 v = (f32x4){0.f, 0.f, 0.f, 0.f};
      if (arow) v = *(const f32x4*)(arow + kk + half * 16 + c * 4);
#pragma unroll
      for (int j = 0; j < 4; j++) Ss[(half * 16 + c * 4 + j) * 132 + tr] = v[j];
      f32x4 w = *(const f32x4*)(wrow + kk + half * 16 + c * 4);
#pragma unroll
      for (int j = 0; j < 4; j++) Ws[(half * 16 + c * 4 + j) * 132 + tr] = w[j];
    }
    __syncthreads();
    const int ty = tid >> 4, tx = tid & 15;
    for (int k = 0; k < 32; k++) {
      f32x4 s0 = *(const f32x4*)&Ss[k * 132 + ty * 4];
      f32x4 s1 = *(const f32x4*)&Ss[k * 132 + 64 + ty * 4];
      f32x4 m0 = *(const f32x4*)&Ws[k * 132 + tx * 4];
      f32x4 m1 = *(const f32x4*)&Ws[k * 132 + 64 + tx * 4];
#pragma unroll
      for (int i = 0; i < 4; i++) {
#pragma unroll
        for (int j = 0; j < 4; j++) {
          acc[i][j]         += s0[i] * m0[j];
          acc[i][j + 4]     += s0[i] * m1[j];
          acc[i + 4][j]     += s1[i] * m0[j];
          acc[i + 4][j + 4] += s1[i] * m1[j];
        }
      }
    }
  }
  const int ty = tid >> 4, tx = tid & 15;
#pragma unroll
  for (int ri = 0; ri < 2; ri++) {
#pragma unroll
    for (int i = 0; i < 4; i++) {
      int t = t0 + ri * 64 + ty * 4 + i;
      if (t >= MM) continue;
      size_t rb = ((size_t)(b * MM + t)) * HID;
#pragma unroll
      for (int oi = 0; oi < 2; oi++) {
        int o = o0 + oi * 64 + tx * 4;
        if (fmt) {
          f32x4 v;
#pragma unroll
          for (int j = 0; j < 4; j++) v[j] = acc[ri * 4 + i][oi * 4 + j];
          *(f32x4*)((float*)P + rb + o) = v;
        } else {
          ushort4 pk;
          pk.x = f2bf(acc[ri * 4 + i][oi * 4 + 0]);
          pk.y = f2bf(acc[ri * 4 + i][oi * 4 + 1]);
          pk.z = f2bf(acc[ri * 4 + i][oi * 4 + 2]);
          pk.w = f2bf(acc[ri * 4 + i][oi * 4 + 3]);
          *(ushort4*)((us*)P + rb + o) = pk;
        }
      }
    }
  }
}

// ---------------------------------------------------------------------------
// Staging helper: Xs[d][m] = P[b, m0+m (clamped), h*64+d], 64x64, stride 68.
// ---------------------------------------------------------------------------
__device__ __forceinline__ void stage_slab(
    float* Xs, const void* P_, int b, int r0, int h, int tid, int fmt) {
  const int m = tid >> 2, c = tid & 3;
  const size_t row = (size_t)(b * MM + min(r0 + m, MM - 1));
  if (fmt) {
    const float* p = (const float*)P_ + row * HID + h * DH + c * 16;
#pragma unroll
    for (int q = 0; q < 4; q++) {
      f32x4 v = *(const f32x4*)(p + q * 4);
#pragma unroll
      for (int j = 0; j < 4; j++) Xs[(c * 16 + q * 4 + j) * 68 + m] = v[j];
    }
  } else {
    const us* p = (const us*)P_ + row * HID + h * DH + c * 16;
#pragma unroll
    for (int q = 0; q < 2; q++) {
      uint4 v = *(const uint4*)(p + q * 8);
      const us* vp = (const us*)&v;
#pragma unroll
      for (int j = 0; j < 8; j++) Xs[(c * 16 + q * 8 + j) * 68 + m] = bf2f(vp[j]);
    }
  }
}

// ---------------------------------------------------------------------------
// K2: sums. For one (b,h), 64x64 aff tile: e=exp(aff) (0 if masked/pad),
// atomically accumulate row sums (over n -> Sums[0]) and col sums (over m
// -> Sums[1]). No max subtraction: logits bounded ~50, exp fits f32.
// ---------------------------------------------------------------------------
__global__ __launch_bounds__(256) void sums_kernel(
    const void* __restrict__ Px_, const void* __restrict__ Py_,
    const int* __restrict__ mx, const int* __restrict__ my,
    float* __restrict__ Sums, const int fmt) {
  const int n0 = blockIdx.x * 64, m0 = blockIdx.y * 64;
  const int b = blockIdx.z >> 4, h = blockIdx.z & 15;
  __shared__ __align__(16) float Xs[64 * 68];
  __shared__ __align__(16) float Ys[64 * 68];
  __shared__ float rS[64], cS[64];
  const int tid = threadIdx.x;
  if (tid < 64) { rS[tid] = 0.f; cS[tid] = 0.f; }
  stage_slab(Xs, Px_, b, m0, h, tid, fmt);
  stage_slab(Ys, Py_, b, n0, h, tid, fmt);
  __syncthreads();

  const int ty = tid >> 4, tx = tid & 15;
  float ac[4][4];
#pragma unroll
  for (int i = 0; i < 4; i++)
#pragma unroll
    for (int j = 0; j < 4; j++) ac[i][j] = 0.f;
  for (int d = 0; d < DH; d++) {
    f32x4 xv = *(const f32x4*)&Xs[d * 68 + ty * 4];
    f32x4 yv = *(const f32x4*)&Ys[d * 68 + tx * 4];
#pragma unroll
    for (int i = 0; i < 4; i++)
#pragma unroll
      for (int j = 0; j < 4; j++) ac[i][j] += xv[i] * yv[j];
  }
  int rm[4], cm[4];
#pragma unroll
  for (int i = 0; i < 4; i++) {
    int m = m0 + ty * 4 + i;
    rm[i] = (m >= MM) ? 0 : ((m < 2) ? 1 : mx[b * SEQ + m - 2]);
  }
#pragma unroll
  for (int j = 0; j < 4; j++) {
    int n = n0 + tx * 4 + j;
    cm[j] = (n >= MM) ? 0 : ((n < 2) ? 1 : my[b * SEQ + n - 2]);
  }
  float csum[4] = {0.f, 0.f, 0.f, 0.f};
#pragma unroll
  for (int i = 0; i < 4; i++) {
    float rsum = 0.f;
#pragma unroll
    for (int j = 0; j < 4; j++) {
      float e = (rm[i] && cm[j]) ? __expf(ac[i][j]) : 0.f;
      rsum += e;
      csum[j] += e;
    }
    atomicAdd(&rS[ty * 4 + i], rsum);
  }
#pragma unroll
  for (int j = 0; j < 4; j++) atomicAdd(&cS[tx * 4 + j], csum[j]);
  __syncthreads();
  const size_t base = ((size_t)(b * NH + h)) * MM;
  const size_t COLOFF = (size_t)B_ * NH * MM;
  if (tid < 64) {
    int m = m0 + tid;
    if (m < MM) atomicAdd(&Sums[base + m], rS[tid]);
  } else if (tid < 128) {
    int n = n0 + (tid - 64);
    if (n < MM) atomicAdd(&Sums[COLOFF + base + n], cS[tid - 64]);
  }
}

// ---------------------------------------------------------------------------
// K2b: invert sums in place; S==0 (fully masked) -> sentinel -1 (uniform).
// ---------------------------------------------------------------------------
__global__ __launch_bounds__(256) void inv_kernel(float* __restrict__ Sums) {
  int i = blockIdx.x * 256 + threadIdx.x;
  if (i < 2 * B_ * NH * MM) {
    float s = Sums[i];
    Sums[i] = (s > 0.f) ? (1.f / s) : -1.f;
  }
}

// ---------------------------------------------------------------------------
// K3: attn. Recompute e per head, accumulate head-mean normalized softmaxes.
// attn_Y uses row inv (Sums[0], idx m); attn_X uses col inv (Sums[1], idx n).
// inv<0 sentinel -> uniform 1/514. attn stored bf16.
// ---------------------------------------------------------------------------
__global__ __launch_bounds__(256) void attn_kernel(
    const void* __restrict__ Px_, const void* __restrict__ Py_,
    const int* __restrict__ mx, const int* __restrict__ my,
    const float* __restrict__ Inv,
    us* __restrict__ attnX, us* __restrict__ attnY,
    const int doX, const int doY, const int fmt) {
  const int n0 = blockIdx.x * 64, m0 = blockIdx.y * 64;
  const int b = blockIdx.z;
  __shared__ __align__(16) float Xs[64 * 68];
  __shared__ __align__(16) float Ys[64 * 68];
  const int tid = threadIdx.x;
  const int ty = tid >> 4, tx = tid & 15;
  const size_t COLOFF = (size_t)B_ * NH * MM;

  int rm[4], cm[4], mi[4], nj[4];
#pragma unroll
  for (int i = 0; i < 4; i++) {
    mi[i] = m0 + ty * 4 + i;
    rm[i] = (mi[i] >= MM) ? 0 : ((mi[i] < 2) ? 1 : mx[b * SEQ + mi[i] - 2]);
  }
#pragma unroll
  for (int j = 0; j < 4; j++) {
    nj[j] = n0 + tx * 4 + j;
    cm[j] = (nj[j] >= MM) ? 0 : ((nj[j] < 2) ? 1 : my[b * SEQ + nj[j] - 2]);
  }

  float aX[4][4], aY[4][4];
#pragma unroll
  for (int i = 0; i < 4; i++)
#pragma unroll
    for (int j = 0; j < 4; j++) { aX[i][j] = 0.f; aY[i][j] = 0.f; }

  for (int h = 0; h < NH; h++) {
    __syncthreads();
    stage_slab(Xs, Px_, b, m0, h, tid, fmt);
    stage_slab(Ys, Py_, b, n0, h, tid, fmt);
    __syncthreads();
    float ac[4][4];
#pragma unroll
    for (int i = 0; i < 4; i++)
#pragma unroll
      for (int j = 0; j < 4; j++) ac[i][j] = 0.f;
    for (int d = 0; d < DH; d++) {
      f32x4 xv = *(const f32x4*)&Xs[d * 68 + ty * 4];
      f32x4 yv = *(const f32x4*)&Ys[d * 68 + tx * 4];
#pragma unroll
      for (int i = 0; i < 4; i++)
#pragma unroll
        for (int j = 0; j < 4; j++) ac[i][j] += xv[i] * yv[j];
    }
    const size_t base = ((size_t)(b * NH + h)) * MM;
    float invR[4], invC[4];
#pragma unroll
    for (int i = 0; i < 4; i++) invR[i] = Inv[base + min(mi[i], MM - 1)];
#pragma unroll
    for (int j = 0; j < 4; j++) invC[j] = Inv[COLOFF + base + min(nj[j], MM - 1)];
#pragma unroll
    for (int i = 0; i < 4; i++) {
#pragma unroll
      for (int j = 0; j < 4; j++) {
        float e = (rm[i] && cm[j]) ? __expf(ac[i][j]) : 0.f;
        aY[i][j] += (invR[i] < 0.f) ? UNI : e * invR[i];
        aX[i][j] += (invC[j] < 0.f) ? UNI : e * invC[j];
      }
    }
  }
#pragma unroll
  for (int i = 0; i < 4; i++) {
    if (mi[i] >= MM) continue;
#pragma unroll
    for (int j = 0; j < 4; j++) {
      if (nj[j] >= MM) continue;
      size_t idx = ((size_t)(b * MM + mi[i])) * MM + nj[j];
      if (doX) attnX[idx] = f2bf(aX[i][j] * 0.0625f);
      if (doY) attnY[idx] = f2bf(aY[i][j] * 0.0625f);
    }
  }
}

// ---------------------------------------------------------------------------
// K4: out[r,o] = sum_k S(k,r)*Mem(k,o). attn bf16, Mem f32, OUT F32.
// trans=1: S(k,r)=attn[k][2+r] (X_in_Y); trans=0: S(k,r)=attn[2+r][k].
// ---------------------------------------------------------------------------
__global__ __launch_bounds__(256) void outg_kernel(
    const us* __restrict__ attn, const float* __restrict__ tin,
    const float* __restrict__ mvec, float* __restrict__ outp, const int trans) {
  const int otile = blockIdx.x, rtile = blockIdx.y, b = blockIdx.z;
  __shared__ __align__(16) float Ss[32 * 132];
  __shared__ __align__(16) float Ms[32 * 132];
  const int tid = threadIdx.x;
  const int r0 = rtile * 128, o0 = otile * 128;

  float acc[8][8];
#pragma unroll
  for (int i = 0; i < 8; i++)
#pragma unroll
    for (int j = 0; j < 8; j++) acc[i][j] = 0.f;

  for (int kk = 0; kk < 544; kk += 32) {
    __syncthreads();
    if (trans) {
      int rq = (tid & 31) * 4;
      int kr = tid >> 5;
#pragma unroll
      for (int kb = 0; kb < 32; kb += 8) {
        int k = kr + kb;
        int kg = kk + k;
        if (kg < MM) {
          const us* src = attn + ((size_t)(b * MM + kg)) * MM + 2 + r0 + rq;
          Ss[k * 132 + rq + 0] = bf2f(src[0]);
          Ss[k * 132 + rq + 1] = bf2f(src[1]);
          Ss[k * 132 + rq + 2] = bf2f(src[2]);
          Ss[k * 132 + rq + 3] = bf2f(src[3]);
        } else {
          Ss[k * 132 + rq + 0] = 0.f;
          Ss[k * 132 + rq + 1] = 0.f;
          Ss[k * 132 + rq + 2] = 0.f;
          Ss[k * 132 + rq + 3] = 0.f;
        }
      }
    } else {
      int r = tid >> 1;
      int kh = (tid & 1) * 16;
      const us* src = attn + ((size_t)(b * MM + 2 + r0 + r)) * MM;
#pragma unroll
      for (int j = 0; j < 16; j++) {
        int k = kh + j;
        int kg = kk + k;
        Ss[k * 132 + r] = (kg < MM) ? bf2f(src[kg]) : 0.f;
      }
    }
    {
      int k = tid >> 3;
      int oq = (tid & 7) * 16;
      int kg = kk + k;
      const float* mr = (kg < 2) ? (mvec + (size_t)kg * HID)
                      : (kg < MM) ? (tin + ((size_t)(b * SEQ + kg - 2)) * HID)
                                  : nullptr;
#pragma unroll
      for (int q = 0; q < 4; q++) {
        f32x4 v = (f32x4){0.f, 0.f, 0.f, 0.f};
        if (mr) v = *(const f32x4*)(mr + o0 + oq + q * 4);
        *(f32x4*)&Ms[k * 132 + oq + q * 4] = v;
      }
    }
    __syncthreads();
    const int ty = tid >> 4, tx = tid & 15;
    for (int k = 0; k < 32; k++) {
      f32x4 s0 = *(const f32x4*)&Ss[k * 132 + ty * 4];
      f32x4 s1 = *(const f32x4*)&Ss[k * 132 + 64 + ty * 4];
      f32x4 m0 = *(const f32x4*)&Ms[k * 132 + tx * 4];
      f32x4 m1 = *(const f32x4*)&Ms[k * 132 + 64 + tx * 4];
#pragma unroll
      for (int i = 0; i < 4; i++) {
#pragma unroll
        for (int j = 0; j < 4; j++) {
          acc[i][j]         += s0[i] * m0[j];
          acc[i][j + 4]     += s0[i] * m1[j];
          acc[i + 4][j]     += s1[i] * m0[j];
          acc[i + 4][j + 4] += s1[i] * m1[j];
        }
      }
    }
  }
  const int ty = tid >> 4, tx = tid & 15;
#pragma unroll
  for (int ri = 0; ri < 2; ri++) {
#pragma unroll
    for (int i = 0; i < 4; i++) {
      int r = r0 + ri * 64 + ty * 4 + i;
      size_t rowbase = ((size_t)(b * SEQ + r)) * HID;
#pragma unroll
      for (int oi = 0; oi < 2; oi++) {
        int o = o0 + oi * 64 + tx * 4;
        f32x4 v;
#pragma unroll
        for (int j = 0; j < 4; j++) v[j] = acc[ri * 4 + i][oi * 4 + j];
        *(f32x4*)&outp[rowbase + o] = v;   // OUTPUT IS FLOAT32
      }
    }
  }
}

// ---------------------------------------------------------------------------
extern "C" void kernel_launch(void* const* d_in, const int* in_sizes, int n_in,
                              void* d_out, int out_size, void* d_ws, size_t ws_size,
                              hipStream_t stream) {
  const float* x  = (const float*)d_in[0];
  const float* y  = (const float*)d_in[1];
  const int* mask_x = (const int*)d_in[2];
  const int* mask_y = (const int*)d_in[3];
  const float* Wx = (const float*)d_in[4];
  const float* Wy = (const float*)d_in[5];
  const float* xm = (const float*)d_in[6];
  const float* ym = (const float*)d_in[7];
  float* out = (float*)d_out;

  const size_t szSums = (size_t)2 * B_ * NH * MM * 4;  //  1,052,672
  const size_t szPf   = (size_t)B_ * MM * HID * 4;     // 33,685,504
  const size_t szPb   = (size_t)B_ * MM * HID * 2;     // 16,842,752
  const size_t szAtt  = (size_t)B_ * MM * MM * 2;      //  8,454,272

  const int fmt    = (ws_size >= szSums + 2 * szPf + szAtt) ? 1 : 0;
  const size_t szP = fmt ? szPf : szPb;
  const int dual   = (ws_size >= szSums + 2 * szP + 2 * szAtt) ? 1 : 0;

  char* ws = (char*)d_ws;
  float* Sums = (float*)(ws);
  void* Px = (void*)(ws + szSums);
  void* Py = (void*)(ws + szSums + szP);
  us* A0 = (us*)(ws + szSums + 2 * szP);
  us* A1 = dual ? (us*)(ws + szSums + 2 * szP + szAtt) : A0;

  proj_kernel<<<dim3(8, 5, 16), 256, 0, stream>>>(x, xm, Wx, Px, fmt);
  proj_kernel<<<dim3(8, 5, 16), 256, 0, stream>>>(y, ym, Wy, Py, fmt);
  hipMemsetAsync(Sums, 0, szSums, stream);
  sums_kernel<<<dim3(9, 9, 256), 256, 0, stream>>>(Px, Py, mask_x, mask_y, Sums, fmt);
  inv_kernel<<<dim3((2 * B_ * NH * MM + 255) / 256), 256, 0, stream>>>(Sums);

  if (dual) {
    attn_kernel<<<dim3(9, 9, 16), 256, 0, stream>>>(Px, Py, mask_x, mask_y, Sums, A0, A1, 1, 1, fmt);
    outg_kernel<<<dim3(8, 4, 16), 256, 0, stream>>>(A0, x, xm, out, 1);
    outg_kernel<<<dim3(8, 4, 16), 256, 0, stream>>>(A1, y, ym, out + (size_t)B_ * SEQ * HID, 0);
  } else {
    attn_kernel<<<dim3(9, 9, 16), 256, 0, stream>>>(Px, Py, mask_x, mask_y, Sums, A0, A0, 1, 0, fmt);
    outg_kernel<<<dim3(8, 4, 16), 256, 0, stream>>>(A0, x, xm, out, 1);
    attn_kernel<<<dim3(9, 9, 16), 256, 0, stream>>>(Px, Py, mask_x, mask_y, Sums, A0, A0, 0, 1, fmt);
    outg_kernel<<<dim3(8, 4, 16), 256, 0, stream>>>(A0, y, ym, out + (size_t)B_ * SEQ * HID, 0);
  }
}

// Round 8
// 694.550 us; speedup vs baseline: 2.1886x; 2.1886x over previous
//
#include <hip/hip_runtime.h>

#define B_   16
#define SEQ  512
#define MM   514      // SEQ + 2 memory tokens
#define HID  1024
#define NH   16
#define DH   64
#define UNI  (1.0f/514.0f)

typedef unsigned short us;
typedef __attribute__((ext_vector_type(4))) float f32x4;
typedef __attribute__((ext_vector_type(8))) short short8;  // MFMA A/B frag (8 bf16)

__device__ __forceinline__ us f2bf(float f) {  // RNE f32->bf16
  unsigned int u = __float_as_uint(f);
  u = (u + 0x7FFFu + ((u >> 16) & 1u)) >> 16;
  return (us)u;
}
__device__ __forceinline__ float bf2f(us h) {
  return __uint_as_float(((unsigned int)h) << 16);
}
// pack 8 consecutive f32 -> 8 bf16 (uint4)
__device__ __forceinline__ uint4 pack8(const float* p) {
  f32x4 v0 = *(const f32x4*)p;
  f32x4 v1 = *(const f32x4*)(p + 4);
  uint4 r;
  r.x = (unsigned)f2bf(v0[0]) | ((unsigned)f2bf(v0[1]) << 16);
  r.y = (unsigned)f2bf(v0[2]) | ((unsigned)f2bf(v0[3]) << 16);
  r.z = (unsigned)f2bf(v1[0]) | ((unsigned)f2bf(v1[1]) << 16);
  r.w = (unsigned)f2bf(v1[2]) | ((unsigned)f2bf(v1[3]) << 16);
  return r;
}

// ---------------------------------------------------------------------------
// K1: proj MFMA. P[b,t,o] = sum_k Mem(t,k)*W[o,k], both k-contiguous (A.Bt).
// f32 inputs converted to bf16 during LDS staging. P stored bf16.
// 64x64 tile, 4 waves; C/D layout col=lane&15, row=(lane>>4)*4+reg (verified).
// ---------------------------------------------------------------------------
__global__ __launch_bounds__(256) void proj_mfma(
    const float* __restrict__ tin, const float* __restrict__ mvec,
    const float* __restrict__ W, us* __restrict__ P) {
  const int otile = blockIdx.x, ttile = blockIdx.y, b = blockIdx.z;
  __shared__ __align__(16) us Asm[64 * 40];
  __shared__ __align__(16) us Bsm[64 * 40];
  const int tid = threadIdx.x;
  const int lane = tid & 63, wave = tid >> 6;
  const int c = lane & 15, q = lane >> 4;
  const int srow = tid >> 2, sq = tid & 3;   // 64 rows x 4 chunks of 8
  const int t = ttile * 64 + srow;
  const int o = otile * 64 + srow;
  const float* arow = (t < 2) ? (mvec + (size_t)t * HID)
                    : (t < MM) ? (tin + ((size_t)(b * SEQ + t - 2)) * HID)
                               : nullptr;
  const float* wrow = W + (size_t)o * HID;

  f32x4 acc[4];
#pragma unroll
  for (int i = 0; i < 4; i++) acc[i] = (f32x4){0.f, 0.f, 0.f, 0.f};

  for (int kk = 0; kk < HID; kk += 32) {
    __syncthreads();
    uint4 av = {0u, 0u, 0u, 0u};
    if (arow) av = pack8(arow + kk + sq * 8);
    *(uint4*)&Asm[srow * 40 + sq * 8] = av;
    *(uint4*)&Bsm[srow * 40 + sq * 8] = pack8(wrow + kk + sq * 8);
    __syncthreads();
    short8 a0 = *(const short8*)&Asm[(wave * 16 + c) * 40 + q * 8];
#pragma unroll
    for (int ct = 0; ct < 4; ct++) {
      short8 b0 = *(const short8*)&Bsm[(ct * 16 + c) * 40 + q * 8];
      acc[ct] = __builtin_amdgcn_mfma_f32_16x16x32_bf16(a0, b0, acc[ct], 0, 0, 0);
    }
  }
#pragma unroll
  for (int ct = 0; ct < 4; ct++) {
#pragma unroll
    for (int r = 0; r < 4; r++) {
      int tt = ttile * 64 + wave * 16 + q * 4 + r;
      if (tt < MM) {
        int oo = otile * 64 + ct * 16 + c;
        P[((size_t)(b * MM + tt)) * HID + oo] = f2bf(acc[ct][r]);
      }
    }
  }
}

// ---------------------------------------------------------------------------
// shared staging for sums/attn: 64x64 bf16 slab of P (rows clamped), stride 72
// ---------------------------------------------------------------------------
__device__ __forceinline__ void stage_bf(
    us* Xs, const us* P, int b, int r0, int h, int tid) {
#pragma unroll
  for (int i = 0; i < 2; i++) {
    int idx = tid + i * 256;
    int row = idx >> 3, qq = idx & 7;
    *(uint4*)&Xs[row * 72 + qq * 8] =
        *(const uint4*)(P + ((size_t)(b * MM + min(r0 + row, MM - 1))) * HID + h * DH + qq * 8);
  }
}

// ---------------------------------------------------------------------------
// K2: sums MFMA. Per (b,h,mtile,ntile): 64x64 aff via MFMA, e=exp (0 if
// masked/pad), reduce row sums (over n) and col sums (over m), atomically
// accumulate into Sums[0][b,h,m] / Sums[1][b,h,n]. No max subtraction.
// ---------------------------------------------------------------------------
__global__ __launch_bounds__(256) void sums_mfma(
    const us* __restrict__ Px, const us* __restrict__ Py,
    const int* __restrict__ mx, const int* __restrict__ my,
    float* __restrict__ Sums) {
  const int nt = blockIdx.x, mt = blockIdx.y;
  const int b = blockIdx.z >> 4, h = blockIdx.z & 15;
  __shared__ __align__(16) us Xs[64 * 72];
  __shared__ __align__(16) us Ys[64 * 72];
  __shared__ float rS[64], cS[64];
  const int tid = threadIdx.x;
  const int lane = tid & 63, wave = tid >> 6;
  const int c = lane & 15, q = lane >> 4;
  if (tid < 64) cS[tid] = 0.f;
  stage_bf(Xs, Px, b, mt * 64, h, tid);
  stage_bf(Ys, Py, b, nt * 64, h, tid);
  __syncthreads();

  short8 a0 = *(const short8*)&Xs[(wave * 16 + c) * 72 + q * 8];
  short8 a1 = *(const short8*)&Xs[(wave * 16 + c) * 72 + q * 8 + 32];
  int rm[4];
#pragma unroll
  for (int r = 0; r < 4; r++) {
    int m = mt * 64 + wave * 16 + q * 4 + r;
    rm[r] = (m >= MM) ? 0 : ((m < 2) ? 1 : mx[b * SEQ + m - 2]);
  }
  float rowp[4] = {0.f, 0.f, 0.f, 0.f};
#pragma unroll
  for (int s = 0; s < 4; s++) {
    short8 b0 = *(const short8*)&Ys[(s * 16 + c) * 72 + q * 8];
    short8 b1 = *(const short8*)&Ys[(s * 16 + c) * 72 + q * 8 + 32];
    f32x4 av = (f32x4){0.f, 0.f, 0.f, 0.f};
    av = __builtin_amdgcn_mfma_f32_16x16x32_bf16(a0, b0, av, 0, 0, 0);
    av = __builtin_amdgcn_mfma_f32_16x16x32_bf16(a1, b1, av, 0, 0, 0);
    int n = nt * 64 + s * 16 + c;
    int cm = (n >= MM) ? 0 : ((n < 2) ? 1 : my[b * SEQ + n - 2]);
    float colp = 0.f;
#pragma unroll
    for (int r = 0; r < 4; r++) {
      float e = (rm[r] && cm) ? __expf(av[r]) : 0.f;
      rowp[r] += e;
      colp += e;
    }
    // reduce colp over q (lanes xor 16,32): col sum of this wave's 16 rows
    colp += __shfl_xor(colp, 16);
    colp += __shfl_xor(colp, 32);
    if (q == 0) atomicAdd(&cS[s * 16 + c], colp);
  }
  // reduce rowp over the 16 column lanes c
#pragma unroll
  for (int d = 1; d < 16; d <<= 1) {
#pragma unroll
    for (int r = 0; r < 4; r++) rowp[r] += __shfl_xor(rowp[r], d, 16);
  }
  if (c == 0) {
#pragma unroll
    for (int r = 0; r < 4; r++) rS[wave * 16 + q * 4 + r] = rowp[r];
  }
  __syncthreads();
  const size_t base = ((size_t)(b * NH + h)) * MM;
  const size_t COLOFF = (size_t)B_ * NH * MM;
  if (tid < 64) {
    int m = mt * 64 + tid;
    if (m < MM) atomicAdd(&Sums[base + m], rS[tid]);
  } else if (tid < 128) {
    int n = nt * 64 + (tid - 64);
    if (n < MM) atomicAdd(&Sums[COLOFF + base + n], cS[tid - 64]);
  }
}

// ---------------------------------------------------------------------------
// K2b: invert sums in place; S==0 (fully masked) -> sentinel -1 (uniform).
// ---------------------------------------------------------------------------
__global__ __launch_bounds__(256) void inv_kernel(float* __restrict__ Sums) {
  int i = blockIdx.x * 256 + threadIdx.x;
  if (i < 2 * B_ * NH * MM) {
    float s = Sums[i];
    Sums[i] = (s > 0.f) ? (1.f / s) : -1.f;
  }
}

// ---------------------------------------------------------------------------
// K3: attn MFMA. Recompute aff per head, normalize, head-mean accumulate.
// attn_Y uses row inv (idx m); attn_X uses col inv (idx n). Stores bf16.
// ---------------------------------------------------------------------------
__global__ __launch_bounds__(256) void attn_mfma(
    const us* __restrict__ Px, const us* __restrict__ Py,
    const int* __restrict__ mx, const int* __restrict__ my,
    const float* __restrict__ Inv,
    us* __restrict__ attnX, us* __restrict__ attnY,
    const int doX, const int doY) {
  const int nt = blockIdx.x, mt = blockIdx.y, b = blockIdx.z;
  __shared__ __align__(16) us Xs[64 * 72];
  __shared__ __align__(16) us Ys[64 * 72];
  const int tid = threadIdx.x;
  const int lane = tid & 63, wave = tid >> 6;
  const int c = lane & 15, q = lane >> 4;
  const size_t COLOFF = (size_t)B_ * NH * MM;

  int mreg[4], rm[4], ncol[4], cm[4];
#pragma unroll
  for (int r = 0; r < 4; r++) {
    mreg[r] = mt * 64 + wave * 16 + q * 4 + r;
    rm[r] = (mreg[r] >= MM) ? 0 : ((mreg[r] < 2) ? 1 : mx[b * SEQ + mreg[r] - 2]);
  }
#pragma unroll
  for (int s = 0; s < 4; s++) {
    ncol[s] = nt * 64 + s * 16 + c;
    cm[s] = (ncol[s] >= MM) ? 0 : ((ncol[s] < 2) ? 1 : my[b * SEQ + ncol[s] - 2]);
  }

  float aX[4][4], aY[4][4];
#pragma unroll
  for (int s = 0; s < 4; s++)
#pragma unroll
    for (int r = 0; r < 4; r++) { aX[s][r] = 0.f; aY[s][r] = 0.f; }

  for (int h = 0; h < NH; h++) {
    __syncthreads();
    stage_bf(Xs, Px, b, mt * 64, h, tid);
    stage_bf(Ys, Py, b, nt * 64, h, tid);
    __syncthreads();
    short8 a0 = *(const short8*)&Xs[(wave * 16 + c) * 72 + q * 8];
    short8 a1 = *(const short8*)&Xs[(wave * 16 + c) * 72 + q * 8 + 32];
    const size_t base = ((size_t)(b * NH + h)) * MM;
    float invR[4];
#pragma unroll
    for (int r = 0; r < 4; r++) invR[r] = Inv[base + min(mreg[r], MM - 1)];
#pragma unroll
    for (int s = 0; s < 4; s++) {
      float invC = Inv[COLOFF + base + min(ncol[s], MM - 1)];
      short8 b0 = *(const short8*)&Ys[(s * 16 + c) * 72 + q * 8];
      short8 b1 = *(const short8*)&Ys[(s * 16 + c) * 72 + q * 8 + 32];
      f32x4 av = (f32x4){0.f, 0.f, 0.f, 0.f};
      av = __builtin_amdgcn_mfma_f32_16x16x32_bf16(a0, b0, av, 0, 0, 0);
      av = __builtin_amdgcn_mfma_f32_16x16x32_bf16(a1, b1, av, 0, 0, 0);
#pragma unroll
      for (int r = 0; r < 4; r++) {
        float e = (rm[r] && cm[s]) ? __expf(av[r]) : 0.f;
        aY[s][r] += (invR[r] < 0.f) ? UNI : e * invR[r];
        aX[s][r] += (invC < 0.f) ? UNI : e * invC;
      }
    }
  }
#pragma unroll
  for (int s = 0; s < 4; s++) {
#pragma unroll
    for (int r = 0; r < 4; r++) {
      if (mreg[r] < MM && ncol[s] < MM) {
        size_t idx = ((size_t)(b * MM + mreg[r])) * MM + ncol[s];
        if (doX) attnX[idx] = f2bf(aX[s][r] * 0.0625f);
        if (doY) attnY[idx] = f2bf(aY[s][r] * 0.0625f);
      }
    }
  }
}

// ---------------------------------------------------------------------------
// K4: out[r,o] = sum_k S(k,r)*Mem(k,o). attn bf16, Mem f32, OUT f32.
// trans=1: S(k,r)=attn[k][2+r] (X_in_Y); trans=0: S(k,r)=attn[2+r][k].
// f32 VALU 128x128 tile, 8x8 register blocking. (unchanged from r7)
// ---------------------------------------------------------------------------
__global__ __launch_bounds__(256) void outg_kernel(
    const us* __restrict__ attn, const float* __restrict__ tin,
    const float* __restrict__ mvec, float* __restrict__ outp, const int trans) {
  const int otile = blockIdx.x, rtile = blockIdx.y, b = blockIdx.z;
  __shared__ __align__(16) float Ss[32 * 132];
  __shared__ __align__(16) float Ms[32 * 132];
  const int tid = threadIdx.x;
  const int r0 = rtile * 128, o0 = otile * 128;

  float acc[8][8];
#pragma unroll
  for (int i = 0; i < 8; i++)
#pragma unroll
    for (int j = 0; j < 8; j++) acc[i][j] = 0.f;

  for (int kk = 0; kk < 544; kk += 32) {
    __syncthreads();
    if (trans) {
      int rq = (tid & 31) * 4;
      int kr = tid >> 5;
#pragma unroll
      for (int kb = 0; kb < 32; kb += 8) {
        int k = kr + kb;
        int kg = kk + k;
        if (kg < MM) {
          const us* src = attn + ((size_t)(b * MM + kg)) * MM + 2 + r0 + rq;
          Ss[k * 132 + rq + 0] = bf2f(src[0]);
          Ss[k * 132 + rq + 1] = bf2f(src[1]);
          Ss[k * 132 + rq + 2] = bf2f(src[2]);
          Ss[k * 132 + rq + 3] = bf2f(src[3]);
        } else {
          Ss[k * 132 + rq + 0] = 0.f;
          Ss[k * 132 + rq + 1] = 0.f;
          Ss[k * 132 + rq + 2] = 0.f;
          Ss[k * 132 + rq + 3] = 0.f;
        }
      }
    } else {
      int r = tid >> 1;
      int kh = (tid & 1) * 16;
      const us* src = attn + ((size_t)(b * MM + 2 + r0 + r)) * MM;
#pragma unroll
      for (int j = 0; j < 16; j++) {
        int k = kh + j;
        int kg = kk + k;
        Ss[k * 132 + r] = (kg < MM) ? bf2f(src[kg]) : 0.f;
      }
    }
    {
      int k = tid >> 3;
      int oq = (tid & 7) * 16;
      int kg = kk + k;
      const float* mr = (kg < 2) ? (mvec + (size_t)kg * HID)
                      : (kg < MM) ? (tin + ((size_t)(b * SEQ + kg - 2)) * HID)
                                  : nullptr;
#pragma unroll
      for (int qq = 0; qq < 4; qq++) {
        f32x4 v = (f32x4){0.f, 0.f, 0.f, 0.f};
        if (mr) v = *(const f32x4*)(mr + o0 + oq + qq * 4);
        *(f32x4*)&Ms[k * 132 + oq + qq * 4] = v;
      }
    }
    __syncthreads();
    const int ty = tid >> 4, tx = tid & 15;
    for (int k = 0; k < 32; k++) {
      f32x4 s0 = *(const f32x4*)&Ss[k * 132 + ty * 4];
      f32x4 s1 = *(const f32x4*)&Ss[k * 132 + 64 + ty * 4];
      f32x4 m0 = *(const f32x4*)&Ms[k * 132 + tx * 4];
      f32x4 m1 = *(const f32x4*)&Ms[k * 132 + 64 + tx * 4];
#pragma unroll
      for (int i = 0; i < 4; i++) {
#pragma unroll
        for (int j = 0; j < 4; j++) {
          acc[i][j]         += s0[i] * m0[j];
          acc[i][j + 4]     += s0[i] * m1[j];
          acc[i + 4][j]     += s1[i] * m0[j];
          acc[i + 4][j + 4] += s1[i] * m1[j];
        }
      }
    }
  }
  const int ty = tid >> 4, tx = tid & 15;
#pragma unroll
  for (int ri = 0; ri < 2; ri++) {
#pragma unroll
    for (int i = 0; i < 4; i++) {
      int r = r0 + ri * 64 + ty * 4 + i;
      size_t rowbase = ((size_t)(b * SEQ + r)) * HID;
#pragma unroll
      for (int oi = 0; oi < 2; oi++) {
        int o = o0 + oi * 64 + tx * 4;
        f32x4 v;
#pragma unroll
        for (int j = 0; j < 4; j++) v[j] = acc[ri * 4 + i][oi * 4 + j];
        *(f32x4*)&outp[rowbase + o] = v;
      }
    }
  }
}

// ---------------------------------------------------------------------------
extern "C" void kernel_launch(void* const* d_in, const int* in_sizes, int n_in,
                              void* d_out, int out_size, void* d_ws, size_t ws_size,
                              hipStream_t stream) {
  const float* x  = (const float*)d_in[0];
  const float* y  = (const float*)d_in[1];
  const int* mask_x = (const int*)d_in[2];
  const int* mask_y = (const int*)d_in[3];
  const float* Wx = (const float*)d_in[4];
  const float* Wy = (const float*)d_in[5];
  const float* xm = (const float*)d_in[6];
  const float* ym = (const float*)d_in[7];
  float* out = (float*)d_out;

  const size_t szSums = (size_t)2 * B_ * NH * MM * 4;  //  1,052,672
  const size_t szP    = (size_t)B_ * MM * HID * 2;     // 16,842,752 (bf16)
  const size_t szAtt  = (size_t)B_ * MM * MM * 2;      //  8,454,272 (bf16)

  const int dual = (ws_size >= szSums + 2 * szP + 2 * szAtt) ? 1 : 0;

  char* ws = (char*)d_ws;
  float* Sums = (float*)(ws);
  us* Px = (us*)(ws + szSums);
  us* Py = (us*)(ws + szSums + szP);
  us* A0 = (us*)(ws + szSums + 2 * szP);
  us* A1 = dual ? (us*)(ws + szSums + 2 * szP + szAtt) : A0;

  proj_mfma<<<dim3(16, 9, 16), 256, 0, stream>>>(x, xm, Wx, Px);
  proj_mfma<<<dim3(16, 9, 16), 256, 0, stream>>>(y, ym, Wy, Py);
  hipMemsetAsync(Sums, 0, szSums, stream);
  sums_mfma<<<dim3(9, 9, 256), 256, 0, stream>>>(Px, Py, mask_x, mask_y, Sums);
  inv_kernel<<<dim3((2 * B_ * NH * MM + 255) / 256), 256, 0, stream>>>(Sums);

  if (dual) {
    attn_mfma<<<dim3(9, 9, 16), 256, 0, stream>>>(Px, Py, mask_x, mask_y, Sums, A0, A1, 1, 1);
    outg_kernel<<<dim3(8, 4, 16), 256, 0, stream>>>(A0, x, xm, out, 1);
    outg_kernel<<<dim3(8, 4, 16), 256, 0, stream>>>(A1, y, ym, out + (size_t)B_ * SEQ * HID, 0);
  } else {
    attn_mfma<<<dim3(9, 9, 16), 256, 0, stream>>>(Px, Py, mask_x, mask_y, Sums, A0, A0, 1, 0);
    outg_kernel<<<dim3(8, 4, 16), 256, 0, stream>>>(A0, x, xm, out, 1);
    attn_mfma<<<dim3(9, 9, 16), 256, 0, stream>>>(Px, Py, mask_x, mask_y, Sums, A0, A0, 0, 1);
    outg_kernel<<<dim3(8, 4, 16), 256, 0, stream>>>(A0, y, ym, out + (size_t)B_ * SEQ * HID, 0);
  }
}